// Round 10
// baseline (214.773 us; speedup 1.0000x reference)
//
#include <hip/hip_runtime.h>
#include <hip/hip_bf16.h>
#include <stdint.h>
#include <stddef.h>

// ---------------------------------------------------------------------------
// Quantized LSTM cell (B=4096, I=H=1024) with JAX threefry noise reproduction.
//
// ONE bf16 MFMA GEMM over real-K=2048, A-shared hi/lo B:
//   A  [4096][2048] = [qS8(input) | qS8(hx)]          (exact in bf16)
//   B^T[4096][4096] = cols k<2048: bf16_hi(Weff), k>=2048: bf16_lo(Weff)
//   B columns PERMUTED: col' = 4*h + gate  -> LSTM epilogue fused into GEMM.
//
// R10: R8/R9 geometry (256Mx128N, 4 waves, 2x32KB buffers, 2 blocks/CU) with
//   * mfma_f32_32x32x16_bf16 (2382 vs 2075 TF ubench, half the instructions)
//   * all 8 stage loads issued at tile head (vmcnt(0) at tile end ~free)
//   * 1-cluster-ahead ds_read pipelining (latency hides under MFMA)
// Epilogue: hardware v_exp/v_rcp activations (R7-proven).
// ---------------------------------------------------------------------------

#define PART 1

typedef __attribute__((ext_vector_type(8))) short bf16x8;
typedef __attribute__((ext_vector_type(16))) float f32x16;

#define BATCH 4096

// ---- workspace layout (bytes) ----
#define WS_A_OFF    ((size_t)0)                 // ushort[4096*2048]   16 MiB
#define WS_B_OFF    ((size_t)16 << 20)          // ushort[4096*4096]   32 MiB
#define WS_BIAS_OFF ((size_t)48 << 20)          // float [4096]
#define WS_MAX_OFF  (WS_BIAS_OFF + 16384)       // uint32[4]

// ---------------- threefry2x32 (exact JAX algorithm) ----------------
__host__ __device__ inline void tf2x32(uint32_t k0, uint32_t k1,
                                       uint32_t x0, uint32_t x1,
                                       uint32_t &o0, uint32_t &o1)
{
  const uint32_t k2 = k0 ^ k1 ^ 0x1BD11BDAu;
#define TFR(r) { x0 += x1; x1 = (x1 << (r)) | (x1 >> (32 - (r))); x1 ^= x0; }
  x0 += k0; x1 += k1;
  TFR(13) TFR(15) TFR(26) TFR(6)
  x0 += k1; x1 += k2 + 1u;
  TFR(17) TFR(29) TFR(16) TFR(24)
  x0 += k2; x1 += k0 + 2u;
  TFR(13) TFR(15) TFR(26) TFR(6)
  x0 += k0; x1 += k1 + 3u;
  TFR(17) TFR(29) TFR(16) TFR(24)
  x0 += k1; x1 += k2 + 4u;
  TFR(13) TFR(15) TFR(26) TFR(6)
  x0 += k2; x1 += k0 + 5u;
#undef TFR
  o0 = x0; o1 = x1;
}

__device__ inline uint32_t jax_bits32(uint32_t k0, uint32_t k1, uint32_t i, uint32_t size)
{
#if PART
  uint32_t a, b;
  tf2x32(k0, k1, 0u, i, a, b);
  return a ^ b;
#else
  uint32_t half = size >> 1, a, b;
  if (i < half) { tf2x32(k0, k1, i, i + half, a, b); return a; }
  tf2x32(k0, k1, i - half, i, a, b); return b;
#endif
}

// uniform(-1+2^-24, 1) -> sqrt(2)*erfinv(u), XLA f32 ErfInv (Giles) polynomial
__device__ inline float bits_to_normal(uint32_t bits)
{
  float f = __uint_as_float((bits >> 9) | 0x3F800000u) - 1.0f;
  const float lo = -0x1.fffffep-1f;
  float u = fmaxf(lo, f * 2.0f + lo);
  float w = -log1pf(-u * u);
  float p;
  if (w < 5.0f) {
    w -= 2.5f;
    p = 2.81022636e-08f;
    p = fmaf(p, w, 3.43273939e-07f);
    p = fmaf(p, w, -3.5233877e-06f);
    p = fmaf(p, w, -4.39150654e-06f);
    p = fmaf(p, w, 0.00021858087f);
    p = fmaf(p, w, -0.00125372503f);
    p = fmaf(p, w, -0.00417768164f);
    p = fmaf(p, w, 0.246640727f);
    p = fmaf(p, w, 1.50140941f);
  } else {
    w = sqrtf(w) - 3.0f;
    p = -0.000200214257f;
    p = fmaf(p, w, 0.000100950558f);
    p = fmaf(p, w, 0.00134934322f);
    p = fmaf(p, w, -0.00367342844f);
    p = fmaf(p, w, 0.00573950773f);
    p = fmaf(p, w, -0.0076224613f);
    p = fmaf(p, w, 0.00943887047f);
    p = fmaf(p, w, 1.00167406f);
    p = fmaf(p, w, 2.83297682f);
  }
  return 0x1.6a09e6p+0f * (p * u);
}

// ---------------- quantization + fast activation helpers ----------------
__device__ inline float quantS8(float x)
{
  x = fminf(fmaxf(x, -0.9921875f), 0.9921875f);
  return rintf(x * 128.0f) * 0.0078125f;
}
__device__ inline float quantU8(float x)
{
  x = fminf(fmaxf(x, 0.0f), 1.0f);
  return rintf(x * 256.0f) * 0.00390625f;
}

#define LOG2E 1.44269504088896340736f
__device__ inline float sigmoid_fast(float x)
{
  float e = __builtin_amdgcn_exp2f(x * -LOG2E);
  return __builtin_amdgcn_rcpf(1.0f + e);
}
__device__ inline float tanh_fast(float x)
{
  float a = fabsf(x);
  float e = __builtin_amdgcn_exp2f(a * (-2.0f * LOG2E));
  float t = (1.0f - e) * __builtin_amdgcn_rcpf(1.0f + e);
  return copysignf(t, x);
}

__device__ inline unsigned short f2bf(float x)
{
  uint32_t b = __float_as_uint(x);
  return (unsigned short)((b + 0x7FFFu + ((b >> 16) & 1u)) >> 16);
}
__device__ inline float bf2f(unsigned short u) { return __uint_as_float(((uint32_t)u) << 16); }

__device__ inline float dec_max(uint32_t u)
{
  uint32_t bits = (u & 0x80000000u) ? (u ^ 0x80000000u) : ~u;
  return __uint_as_float(bits);
}

// ---------------- fused small kernels ----------------
__global__ void init_max(uint32_t* mx)
{
  if (threadIdx.x < 4) mx[threadIdx.x] = 0u;
}

__global__ void kmax_all(const float4* __restrict__ wih, const float4* __restrict__ whh,
                         const float4* __restrict__ bih, const float4* __restrict__ bhh,
                         uint32_t* __restrict__ mx)
{
  const int blk = blockIdx.x;
  const float4* src; int n4, bl, nb; uint32_t* out;
  if (blk < 1024)      { src = wih; n4 = 1048576; bl = blk;        nb = 1024; out = mx + 0; }
  else if (blk < 2048) { src = whh; n4 = 1048576; bl = blk - 1024; nb = 1024; out = mx + 1; }
  else if (blk < 2052) { src = bih; n4 = 1024;    bl = blk - 2048; nb = 4;    out = mx + 2; }
  else                 { src = bhh; n4 = 1024;    bl = blk - 2052; nb = 4;    out = mx + 3; }

  float m = -3.4e38f;
  for (int i = bl * 256 + threadIdx.x; i < n4; i += nb * 256) {
    float4 v = src[i];
    m = fmaxf(fmaxf(m, fmaxf(v.x, v.y)), fmaxf(v.z, v.w));
  }
  for (int off = 32; off; off >>= 1) m = fmaxf(m, __shfl_down(m, off, 64));
  __shared__ float sm[4];
  if ((threadIdx.x & 63) == 0) sm[threadIdx.x >> 6] = m;
  __syncthreads();
  if (threadIdx.x == 0) {
    float bm = fmaxf(fmaxf(sm[0], sm[1]), fmaxf(sm[2], sm[3]));
    uint32_t bits = __float_as_uint(bm);
    uint32_t enc = (bits & 0x80000000u) ? ~bits : (bits | 0x80000000u);
    atomicMax(out, enc);
  }
}

// blocks [0,16384): B (2 k-elems/thread);  [16384,24576): A;  [24576,24592): bias.
__global__ void build_all(const float* __restrict__ wih, const float* __restrict__ whh,
                          const float4* __restrict__ in, const float4* __restrict__ hxp,
                          const float* __restrict__ bih, const float* __restrict__ bhh,
                          unsigned short* __restrict__ A, unsigned short* __restrict__ B,
                          float* __restrict__ biasE, const uint32_t* __restrict__ mxenc,
                          uint32_t kih0, uint32_t kih1, uint32_t khh0, uint32_t khh1,
                          uint32_t kbi0, uint32_t kbi1, uint32_t kbh0, uint32_t kbh1)
{
  const uint32_t blk = blockIdx.x;
  if (blk < 16384u) {
    uint32_t t = blk * 256u + threadIdx.x;      // 4,194,304 threads, 2 elems each
    uint32_t arr = t >> 21;
    uint32_t r = t & 2097151u;
    uint32_t kp = r & 511u;                     // k-pair index
    uint32_t n = r >> 9;                        // original gate column
    const float* w = arr ? whh : wih;
    float mx = dec_max(mxenc[arr]);
    uint32_t key0 = arr ? khh0 : kih0, key1 = arr ? khh1 : kih1;
    uint32_t k0 = kp * 2u;
    uint32_t hiw = 0u, low = 0u;
#pragma unroll
    for (int e = 0; e < 2; ++e) {
      uint32_t k = k0 + (uint32_t)e;
      float nrm = bits_to_normal(jax_bits32(key0, key1, k * 4096u + n, 4194304u));
      float weff = w[(size_t)n * 1024u + k] + (nrm * mx) * 0.05f;
      unsigned short hi = f2bf(weff);
      unsigned short lob = f2bf(weff - bf2f(hi));
      hiw |= ((uint32_t)hi) << (16 * e);
      low |= ((uint32_t)lob) << (16 * e);
    }
    uint32_t np = (n & 1023u) * 4u + (n >> 10); // permuted column
    size_t base = (size_t)np * 4096u + (arr ? 1024u : 0u) + k0;
    *reinterpret_cast<uint32_t*>(B + base) = hiw;
    *reinterpret_cast<uint32_t*>(B + base + 2048u) = low;
  } else if (blk < 24576u) {
    int t = (int)(blk - 16384u) * 256 + threadIdx.x;
    int b = t >> 9;
    int kq = t & 511;
    float4 v = (kq < 256) ? in[b * 256 + kq] : hxp[b * 256 + (kq - 256)];
    unsigned short o[4];
    o[0] = f2bf(quantS8(v.x)); o[1] = f2bf(quantS8(v.y));
    o[2] = f2bf(quantS8(v.z)); o[3] = f2bf(quantS8(v.w));
    *reinterpret_cast<uint64_t*>(A + (size_t)t * 4) = *reinterpret_cast<uint64_t*>(o);
  } else {
    uint32_t j = (blk - 24576u) * 256u + threadIdx.x;
    float mi = dec_max(mxenc[2]), mh = dec_max(mxenc[3]);
    float ni = (bits_to_normal(jax_bits32(kbi0, kbi1, j, 4096u)) * mi) * 0.05f;
    float nh = (bits_to_normal(jax_bits32(kbh0, kbh1, j, 4096u)) * mh) * 0.05f;
    biasE[(j & 1023u) * 4u + (j >> 10)] = ((bih[j] + ni) + bhh[j]) + nh;
  }
}

// ---------------- MFMA GEMM (32x32x16, A-shared hi/lo) + fused epilogue -----
__device__ __forceinline__ void gload_lds16(const void* g, void* l)
{
  __builtin_amdgcn_global_load_lds((__attribute__((address_space(1))) void*)g,
                                   (__attribute__((address_space(3))) void*)l, 16, 0, 0);
}

#define VM0  asm volatile("s_waitcnt vmcnt(0)" ::: "memory")
#define NOVM
#define SBAR __builtin_amdgcn_s_barrier()
#define SCB  __builtin_amdgcn_sched_barrier(0)

#define BUFSZ 32768   // A(16K) + Bhi(8K) + Blo(8K)

// stage units of tile ts_ into buffer bi_ (256 threads)
#define STAGE_A(ts_, bi_)                                                         \
    { unsigned char* la_ = lds + (bi_) * BUFSZ; const int ka_ = (ts_) * 32;       \
      gload_lds16(Ar0 + ka_, la_ + tid * 16);                                     \
      gload_lds16(Ar1 + ka_, la_ + 4096 + tid * 16);                              \
      gload_lds16(Ar2 + ka_, la_ + 8192 + tid * 16);                              \
      gload_lds16(Ar3 + ka_, la_ + 12288 + tid * 16); }
#define STAGE_BH(ts_, bi_)                                                        \
    { unsigned char* la_ = lds + (bi_) * BUFSZ; const int ka_ = (ts_) * 32;       \
      gload_lds16(Br0 + ka_, la_ + 16384 + tid * 16);                             \
      gload_lds16(Br1 + ka_, la_ + 16384 + 4096 + tid * 16); }
#define STAGE_BL(ts_, bi_)                                                        \
    { unsigned char* la_ = lds + (bi_) * BUFSZ; const int ka_ = (ts_) * 32;       \
      gload_lds16(Br0 + 2048 + ka_, la_ + 24576 + tid * 16);                      \
      gload_lds16(Br1 + 2048 + ka_, la_ + 24576 + 4096 + tid * 16); }

// One real-K tile: 32 x mfma_f32_32x32x16_bf16 per wave in 4 clusters
// (s0*hi, s1*hi, s0*lo, s1*lo).  All staging at tile head; reads pipelined
// one cluster ahead; compiler-counted lgkm gates each cluster.
#define TILE_ONE(t_, BUF_, BUFN_, DO_STAGE_, VM_ASM_)                             \
  {                                                                               \
    const unsigned char* pa_  = lds + (BUF_) * BUFSZ;                             \
    const unsigned char* pbh_ = lds + (BUF_) * BUFSZ + 16384 + wcB;               \
    const unsigned char* pbl_ = lds + (BUF_) * BUFSZ + 24576 + wcB;               \
    bf16x8 a0_[4], a1_[4], bh0_[2], bh1_[2], bl0_[2], bl1_[2];                    \
    if (DO_STAGE_) { STAGE_A((t_) + 1, BUFN_); STAGE_BH((t_) + 1, BUFN_);         \
                     STAGE_BL((t_) + 1, BUFN_); }                                 \
    _Pragma("unroll") for (int n_ = 0; n_ < 2; ++n_)                              \
      bh0_[n_] = *(const bf16x8*)(pbh_ + off0 + n_ * 2048);                       \
    _Pragma("unroll") for (int m_ = 0; m_ < 4; ++m_)                              \
      a0_[m_] = *(const bf16x8*)(pa_ + aoff0 + m_ * 2048);                        \
    _Pragma("unroll") for (int m_ = 0; m_ < 4; ++m_)                              \
      a1_[m_] = *(const bf16x8*)(pa_ + aoff1 + m_ * 2048);                        \
    _Pragma("unroll") for (int n_ = 0; n_ < 2; ++n_)                              \
      bh1_[n_] = *(const bf16x8*)(pbh_ + off1 + n_ * 2048);                       \
    __builtin_amdgcn_s_setprio(1);                                                \
    _Pragma("unroll") for (int m_ = 0; m_ < 4; ++m_)                              \
      _Pragma("unroll") for (int n_ = 0; n_ < 2; ++n_)                            \
        acc[m_][n_] = __builtin_amdgcn_mfma_f32_32x32x16_bf16(a0_[m_], bh0_[n_],  \
                                                              acc[m_][n_], 0, 0, 0); \
    __builtin_amdgcn_s_setprio(0);                                                \
    _Pragma("unroll") for (int n_ = 0; n_ < 2; ++n_)                              \
      bl0_[n_] = *(const bf16x8*)(pbl_ + off0 + n_ * 2048);                       \
    _Pragma("unroll") for (int n_ = 0; n_ < 2; ++n_)                              \
      bl1_[n_] = *(const bf16x8*)(pbl_ + off1 + n_ * 2048);                       \
    __builtin_amdgcn_s_setprio(1);                                                \
    _Pragma("unroll") for (int m_ = 0; m_ < 4; ++m_)                              \
      _Pragma("unroll") for (int n_ = 0; n_ < 2; ++n_)                            \
        acc[m_][n_] = __builtin_amdgcn_mfma_f32_32x32x16_bf16(a1_[m_], bh1_[n_],  \
                                                              acc[m_][n_], 0, 0, 0); \
    _Pragma("unroll") for (int m_ = 0; m_ < 4; ++m_)                              \
      _Pragma("unroll") for (int n_ = 0; n_ < 2; ++n_)                            \
        acc[m_][n_] = __builtin_amdgcn_mfma_f32_32x32x16_bf16(a0_[m_], bl0_[n_],  \
                                                              acc[m_][n_], 0, 0, 0); \
    _Pragma("unroll") for (int m_ = 0; m_ < 4; ++m_)                              \
      _Pragma("unroll") for (int n_ = 0; n_ < 2; ++n_)                            \
        acc[m_][n_] = __builtin_amdgcn_mfma_f32_32x32x16_bf16(a1_[m_], bl1_[n_],  \
                                                              acc[m_][n_], 0, 0, 0); \
    __builtin_amdgcn_s_setprio(0);                                                \
    VM_ASM_;                                                                      \
    SBAR; SCB;                                                                    \
  }

#define LTS 136   // epilogue LDS row stride in floats

__global__ __launch_bounds__(256, 2) void gemm_gates(
    const unsigned short* __restrict__ A,   // [4096][2048] bf16 bits
    const unsigned short* __restrict__ B,   // [4096][4096] bf16 bits, permuted cols
    const float* __restrict__ bias,         // [4096] permuted
    const float* __restrict__ cx,           // [4096][1024]
    float* __restrict__ hy,                 // [4096][1024]
    float* __restrict__ cy)                 // [4096][1024]
{
  extern __shared__ unsigned char lds[];    // 71680 B
  const int tid  = threadIdx.x;
  const int lane = tid & 63;
  const int wave = tid >> 6;                // 0..3
  const int wr = wave >> 1;                 // 0..1  (M)
  const int wc = wave & 1;                  // 0..1  (N)

  // 512 blocks: 16 M-tiles x 32 N-tiles; XCD-chunked swizzle (512 % 8 == 0)
  const int bid = blockIdx.x;
  const int wg  = (bid & 7) * 64 + (bid >> 3);
  const int brow = (wg & 15) * 256;
  const int bcol = (wg >> 4) * 128;         // permuted-column space

  // staging source (inverse-swizzled): chunk c -> p=c>>3, lc=(c&7)^(p&7)
#define CHUNK_SRC(c_, sr_, sk_) \
    { int p_ = (c_) >> 3, lc_ = ((c_) & 7) ^ (p_ & 7); \
      sr_ = p_ * 2 + (lc_ >> 2); sk_ = (lc_ & 3) * 8; }
  int sr, sk;
  CHUNK_SRC(tid,        sr, sk);
  const unsigned short* Ar0 = A + (size_t)(brow + sr) * 2048 + sk;
  const unsigned short* Br0 = B + (size_t)(bcol + sr) * 4096 + sk;
  CHUNK_SRC(tid + 256,  sr, sk);
  const unsigned short* Ar1 = A + (size_t)(brow + sr) * 2048 + sk;
  const unsigned short* Br1 = B + (size_t)(bcol + sr) * 4096 + sk;
  CHUNK_SRC(tid + 512,  sr, sk);
  const unsigned short* Ar2 = A + (size_t)(brow + sr) * 2048 + sk;
  CHUNK_SRC(tid + 768,  sr, sk);
  const unsigned short* Ar3 = A + (size_t)(brow + sr) * 2048 + sk;
#undef CHUNK_SRC

  // 32x32 fragment read offsets. Logical row = base + (lane&31); k-step s:
  // k = s*16 + (lane>>5)*8.  Pair-swizzled layout:
  //   addr(r,k) = (r>>1)*128 + (((r&1)*4 + (k>>3)) ^ ((r>>1)&7))*16 + (k&7)*2
  const int lrh = (lane & 31) >> 1;
  const int cbase = ((lane & 1) << 2) | (lane >> 5);
  const int chk0 = (cbase)     ^ (lrh & 7);
  const int chk1 = (cbase | 2) ^ (lrh & 7);
  const int aoff0 = wr * 8192 + lrh * 128 + chk0 * 16;   // + m*2048
  const int aoff1 = wr * 8192 + lrh * 128 + chk1 * 16;
  const int off0  = lrh * 128 + chk0 * 16;               // B: + wcB + n*2048
  const int off1  = lrh * 128 + chk1 * 16;
  const int wcB   = wc * 4096;

  f32x16 acc[4][2] = {};

  // prologue: stage tile 0 -> buf0
  STAGE_A(0, 0); STAGE_BH(0, 0); STAGE_BL(0, 0);
  VM0;
  SBAR; SCB;

#pragma unroll 1
  for (int t = 0; t < 63; ++t) {
    TILE_ONE(t, (t & 1), ((t + 1) & 1), 1, VM0);
  }
  TILE_ONE(63, 1, 0, 0, NOVM);

  // ---- fused LSTM epilogue (hardware-exp activations) ----
  // acc[m][n]: row = brow + wr*128 + m*32 + (reg&3)+8*(reg>>2)+4*(lane>>5)
  //            col = bcol + wc*64 + n*32 + (lane&31)   (permuted: col = 4h+g)
  float* LT = (float*)lds;
  const int cl0 = wc * 64 + (lane & 31);
  const int rbase = wr * 64 + ((lane >> 5) << 2);
  const int h = tid & 31;                  // 32 h-values per block
  const int hg = (bcol >> 2) + h;

#pragma unroll
  for (int hh = 0; hh < 2; ++hh) {
    __syncthreads();                       // previous half's reads done
#pragma unroll
    for (int mm = 0; mm < 2; ++mm) {
#pragma unroll
      for (int n = 0; n < 2; ++n) {
        const int cl = cl0 + n * 32;
        const float bv = bias[bcol + cl];
#pragma unroll
        for (int reg = 0; reg < 16; ++reg) {
          const int rl = rbase + mm * 32 + (reg & 3) + ((reg >> 2) << 3);
          LT[rl * LTS + cl] = acc[hh * 2 + mm][n][reg] + bv;
        }
      }
    }
    __syncthreads();
#pragma unroll
    for (int i = 0; i < 16; ++i) {
      const int lr = (tid >> 5) * 16 + i;                       // 0..127
      const int grow = brow + ((lr >> 6) << 7) + (hh * 2 + ((lr >> 5) & 1)) * 32
                       + (lr & 31);
      const float4 q = *(const float4*)(LT + lr * LTS + 4 * h); // (in,fg,cell,out)
      const size_t oidx = (size_t)grow * 1024 + hg;
      float ing = quantU8(sigmoid_fast(q.x));
      float fg  = quantU8(sigmoid_fast(q.y));
      float cg  = quantS8(tanh_fast(q.z));
      float og  = quantU8(sigmoid_fast(q.w));
      float c0  = cx[oidx];
      float cyv = quantS8((quantS8(fg * c0) + quantS8(ing * cg)) * 0.5f);
      float hyv = quantS8(og * quantS8(tanh_fast(cyv * 2.0f)));
      hy[oidx] = hyv;
      cy[oidx] = cyv;
    }
  }
}

// ---------------- host ----------------
extern "C" void kernel_launch(void* const* d_in, const int* in_sizes, int n_in,
                              void* d_out, int out_size, void* d_ws, size_t ws_size,
                              hipStream_t stream)
{
  const float* input = (const float*)d_in[0];
  const float* hx    = (const float*)d_in[1];
  const float* cx    = (const float*)d_in[2];
  const float* wih   = (const float*)d_in[3];
  const float* whh   = (const float*)d_in[4];
  const float* bih   = (const float*)d_in[5];
  const float* bhh   = (const float*)d_in[6];
  (void)in_sizes; (void)n_in; (void)ws_size;

  uint8_t* ws = (uint8_t*)d_ws;
  unsigned short* A   = (unsigned short*)(ws + WS_A_OFF);
  unsigned short* B   = (unsigned short*)(ws + WS_B_OFF);
  float* biasE        = (float*)(ws + WS_BIAS_OFF);
  uint32_t* mx        = (uint32_t*)(ws + WS_MAX_OFF);

  uint32_t nk[4][2];
#if PART
  for (int i = 0; i < 4; ++i) tf2x32(0u, 42u, 0u, (uint32_t)i, nk[i][0], nk[i][1]);
#else
  {
    uint32_t w0[4], w1[4];
    for (int i = 0; i < 4; ++i) tf2x32(0u, 42u, (uint32_t)i, (uint32_t)(i + 4), w0[i], w1[i]);
    uint32_t out8[8] = {w0[0], w0[1], w0[2], w0[3], w1[0], w1[1], w1[2], w1[3]};
    for (int i = 0; i < 4; ++i) { nk[i][0] = out8[2 * i]; nk[i][1] = out8[2 * i + 1]; }
  }
#endif

  init_max<<<1, 64, 0, stream>>>(mx);
  kmax_all<<<2056, 256, 0, stream>>>((const float4*)wih, (const float4*)whh,
                                     (const float4*)bih, (const float4*)bhh, mx);
  build_all<<<24592, 256, 0, stream>>>(wih, whh, (const float4*)input, (const float4*)hx,
                                       bih, bhh, A, B, biasE, mx,
                                       nk[0][0], nk[0][1], nk[1][0], nk[1][1],
                                       nk[2][0], nk[2][1], nk[3][0], nk[3][1]);

  float* hy = (float*)d_out;
  float* cyp = hy + (size_t)BATCH * 1024;

  (void)hipFuncSetAttribute((const void*)gemm_gates,
                            hipFuncAttributeMaxDynamicSharedMemorySize, 71680);
  gemm_gates<<<dim3(512), dim3(256), 71680, stream>>>(A, B, biasE, cx, hy, cyp);
}

// Round 11
// 191.335 us; speedup vs baseline: 1.1225x; 1.1225x over previous
//
#include <hip/hip_runtime.h>
#include <hip/hip_bf16.h>
#include <stdint.h>
#include <stddef.h>

// ---------------------------------------------------------------------------
// Quantized LSTM cell (B=4096, I=H=1024) with JAX threefry noise reproduction.
//
// ONE bf16 MFMA GEMM over real-K=2048, A-shared hi/lo B:
//   A  [4096][2048] = [qS8(input) | qS8(hx)]          (exact in bf16)
//   B^T[4096][4096] = cols k<2048: bf16_hi(Weff), k>=2048: bf16_lo(Weff)
//   B columns PERMUTED: col' = 4*h + gate  -> LSTM epilogue fused into GEMM.
//
// R11 = R9 GEMM (proven 131us: 16x16x32 MFMA, 256Mx128N, 4 waves, 2x32KB LDS
// buffers -> 2 blocks/CU, no intra-tile barriers, compiler-counted lgkm,
// one vmcnt(0)+barrier per tile, 16x16-matched XOR swizzle)
// + R10 build_all (B plane built 2 k-elems/thread, uint32 stores).
// Epilogue: hardware v_exp/v_rcp activations (R7-proven).
// ---------------------------------------------------------------------------

#define PART 1

typedef __attribute__((ext_vector_type(8))) short bf16x8;
typedef __attribute__((ext_vector_type(4))) float f32x4;

#define BATCH 4096

// ---- workspace layout (bytes) ----
#define WS_A_OFF    ((size_t)0)                 // ushort[4096*2048]   16 MiB
#define WS_B_OFF    ((size_t)16 << 20)          // ushort[4096*4096]   32 MiB
#define WS_BIAS_OFF ((size_t)48 << 20)          // float [4096]
#define WS_MAX_OFF  (WS_BIAS_OFF + 16384)       // uint32[4]

// ---------------- threefry2x32 (exact JAX algorithm) ----------------
__host__ __device__ inline void tf2x32(uint32_t k0, uint32_t k1,
                                       uint32_t x0, uint32_t x1,
                                       uint32_t &o0, uint32_t &o1)
{
  const uint32_t k2 = k0 ^ k1 ^ 0x1BD11BDAu;
#define TFR(r) { x0 += x1; x1 = (x1 << (r)) | (x1 >> (32 - (r))); x1 ^= x0; }
  x0 += k0; x1 += k1;
  TFR(13) TFR(15) TFR(26) TFR(6)
  x0 += k1; x1 += k2 + 1u;
  TFR(17) TFR(29) TFR(16) TFR(24)
  x0 += k2; x1 += k0 + 2u;
  TFR(13) TFR(15) TFR(26) TFR(6)
  x0 += k0; x1 += k1 + 3u;
  TFR(17) TFR(29) TFR(16) TFR(24)
  x0 += k1; x1 += k2 + 4u;
  TFR(13) TFR(15) TFR(26) TFR(6)
  x0 += k2; x1 += k0 + 5u;
#undef TFR
  o0 = x0; o1 = x1;
}

__device__ inline uint32_t jax_bits32(uint32_t k0, uint32_t k1, uint32_t i, uint32_t size)
{
#if PART
  uint32_t a, b;
  tf2x32(k0, k1, 0u, i, a, b);
  return a ^ b;
#else
  uint32_t half = size >> 1, a, b;
  if (i < half) { tf2x32(k0, k1, i, i + half, a, b); return a; }
  tf2x32(k0, k1, i - half, i, a, b); return b;
#endif
}

// uniform(-1+2^-24, 1) -> sqrt(2)*erfinv(u), XLA f32 ErfInv (Giles) polynomial
__device__ inline float bits_to_normal(uint32_t bits)
{
  float f = __uint_as_float((bits >> 9) | 0x3F800000u) - 1.0f;
  const float lo = -0x1.fffffep-1f;
  float u = fmaxf(lo, f * 2.0f + lo);
  float w = -log1pf(-u * u);
  float p;
  if (w < 5.0f) {
    w -= 2.5f;
    p = 2.81022636e-08f;
    p = fmaf(p, w, 3.43273939e-07f);
    p = fmaf(p, w, -3.5233877e-06f);
    p = fmaf(p, w, -4.39150654e-06f);
    p = fmaf(p, w, 0.00021858087f);
    p = fmaf(p, w, -0.00125372503f);
    p = fmaf(p, w, -0.00417768164f);
    p = fmaf(p, w, 0.246640727f);
    p = fmaf(p, w, 1.50140941f);
  } else {
    w = sqrtf(w) - 3.0f;
    p = -0.000200214257f;
    p = fmaf(p, w, 0.000100950558f);
    p = fmaf(p, w, 0.00134934322f);
    p = fmaf(p, w, -0.00367342844f);
    p = fmaf(p, w, 0.00573950773f);
    p = fmaf(p, w, -0.0076224613f);
    p = fmaf(p, w, 0.00943887047f);
    p = fmaf(p, w, 1.00167406f);
    p = fmaf(p, w, 2.83297682f);
  }
  return 0x1.6a09e6p+0f * (p * u);
}

// ---------------- quantization + fast activation helpers ----------------
__device__ inline float quantS8(float x)
{
  x = fminf(fmaxf(x, -0.9921875f), 0.9921875f);
  return rintf(x * 128.0f) * 0.0078125f;
}
__device__ inline float quantU8(float x)
{
  x = fminf(fmaxf(x, 0.0f), 1.0f);
  return rintf(x * 256.0f) * 0.00390625f;
}

#define LOG2E 1.44269504088896340736f
__device__ inline float sigmoid_fast(float x)
{
  float e = __builtin_amdgcn_exp2f(x * -LOG2E);
  return __builtin_amdgcn_rcpf(1.0f + e);
}
__device__ inline float tanh_fast(float x)
{
  float a = fabsf(x);
  float e = __builtin_amdgcn_exp2f(a * (-2.0f * LOG2E));
  float t = (1.0f - e) * __builtin_amdgcn_rcpf(1.0f + e);
  return copysignf(t, x);
}

__device__ inline unsigned short f2bf(float x)
{
  uint32_t b = __float_as_uint(x);
  return (unsigned short)((b + 0x7FFFu + ((b >> 16) & 1u)) >> 16);
}
__device__ inline float bf2f(unsigned short u) { return __uint_as_float(((uint32_t)u) << 16); }

__device__ inline float dec_max(uint32_t u)
{
  uint32_t bits = (u & 0x80000000u) ? (u ^ 0x80000000u) : ~u;
  return __uint_as_float(bits);
}

// ---------------- fused small kernels ----------------
__global__ void init_max(uint32_t* mx)
{
  if (threadIdx.x < 4) mx[threadIdx.x] = 0u;
}

__global__ void kmax_all(const float4* __restrict__ wih, const float4* __restrict__ whh,
                         const float4* __restrict__ bih, const float4* __restrict__ bhh,
                         uint32_t* __restrict__ mx)
{
  const int blk = blockIdx.x;
  const float4* src; int n4, bl, nb; uint32_t* out;
  if (blk < 1024)      { src = wih; n4 = 1048576; bl = blk;        nb = 1024; out = mx + 0; }
  else if (blk < 2048) { src = whh; n4 = 1048576; bl = blk - 1024; nb = 1024; out = mx + 1; }
  else if (blk < 2052) { src = bih; n4 = 1024;    bl = blk - 2048; nb = 4;    out = mx + 2; }
  else                 { src = bhh; n4 = 1024;    bl = blk - 2052; nb = 4;    out = mx + 3; }

  float m = -3.4e38f;
  for (int i = bl * 256 + threadIdx.x; i < n4; i += nb * 256) {
    float4 v = src[i];
    m = fmaxf(fmaxf(m, fmaxf(v.x, v.y)), fmaxf(v.z, v.w));
  }
  for (int off = 32; off; off >>= 1) m = fmaxf(m, __shfl_down(m, off, 64));
  __shared__ float sm[4];
  if ((threadIdx.x & 63) == 0) sm[threadIdx.x >> 6] = m;
  __syncthreads();
  if (threadIdx.x == 0) {
    float bm = fmaxf(fmaxf(sm[0], sm[1]), fmaxf(sm[2], sm[3]));
    uint32_t bits = __float_as_uint(bm);
    uint32_t enc = (bits & 0x80000000u) ? ~bits : (bits | 0x80000000u);
    atomicMax(out, enc);
  }
}

// blocks [0,16384): B (2 k-elems/thread);  [16384,24576): A;  [24576,24592): bias.
__global__ void build_all(const float* __restrict__ wih, const float* __restrict__ whh,
                          const float4* __restrict__ in, const float4* __restrict__ hxp,
                          const float* __restrict__ bih, const float* __restrict__ bhh,
                          unsigned short* __restrict__ A, unsigned short* __restrict__ B,
                          float* __restrict__ biasE, const uint32_t* __restrict__ mxenc,
                          uint32_t kih0, uint32_t kih1, uint32_t khh0, uint32_t khh1,
                          uint32_t kbi0, uint32_t kbi1, uint32_t kbh0, uint32_t kbh1)
{
  const uint32_t blk = blockIdx.x;
  if (blk < 16384u) {
    uint32_t t = blk * 256u + threadIdx.x;      // 4,194,304 threads, 2 elems each
    uint32_t arr = t >> 21;
    uint32_t r = t & 2097151u;
    uint32_t kp = r & 511u;                     // k-pair index
    uint32_t n = r >> 9;                        // original gate column
    const float* w = arr ? whh : wih;
    float mx = dec_max(mxenc[arr]);
    uint32_t key0 = arr ? khh0 : kih0, key1 = arr ? khh1 : kih1;
    uint32_t k0 = kp * 2u;
    uint32_t hiw = 0u, low = 0u;
#pragma unroll
    for (int e = 0; e < 2; ++e) {
      uint32_t k = k0 + (uint32_t)e;
      float nrm = bits_to_normal(jax_bits32(key0, key1, k * 4096u + n, 4194304u));
      float weff = w[(size_t)n * 1024u + k] + (nrm * mx) * 0.05f;
      unsigned short hi = f2bf(weff);
      unsigned short lob = f2bf(weff - bf2f(hi));
      hiw |= ((uint32_t)hi) << (16 * e);
      low |= ((uint32_t)lob) << (16 * e);
    }
    uint32_t np = (n & 1023u) * 4u + (n >> 10); // permuted column
    size_t base = (size_t)np * 4096u + (arr ? 1024u : 0u) + k0;
    *reinterpret_cast<uint32_t*>(B + base) = hiw;
    *reinterpret_cast<uint32_t*>(B + base + 2048u) = low;
  } else if (blk < 24576u) {
    int t = (int)(blk - 16384u) * 256 + threadIdx.x;
    int b = t >> 9;
    int kq = t & 511;
    float4 v = (kq < 256) ? in[b * 256 + kq] : hxp[b * 256 + (kq - 256)];
    unsigned short o[4];
    o[0] = f2bf(quantS8(v.x)); o[1] = f2bf(quantS8(v.y));
    o[2] = f2bf(quantS8(v.z)); o[3] = f2bf(quantS8(v.w));
    *reinterpret_cast<uint64_t*>(A + (size_t)t * 4) = *reinterpret_cast<uint64_t*>(o);
  } else {
    uint32_t j = (blk - 24576u) * 256u + threadIdx.x;
    float mi = dec_max(mxenc[2]), mh = dec_max(mxenc[3]);
    float ni = (bits_to_normal(jax_bits32(kbi0, kbi1, j, 4096u)) * mi) * 0.05f;
    float nh = (bits_to_normal(jax_bits32(kbh0, kbh1, j, 4096u)) * mh) * 0.05f;
    biasE[(j & 1023u) * 4u + (j >> 10)] = ((bih[j] + ni) + bhh[j]) + nh;
  }
}

// ---------------- MFMA GEMM (A-shared hi/lo) + fused LSTM epilogue ----------
__device__ __forceinline__ void gload_lds16(const void* g, void* l)
{
  __builtin_amdgcn_global_load_lds((__attribute__((address_space(1))) void*)g,
                                   (__attribute__((address_space(3))) void*)l, 16, 0, 0);
}

#define VM0  asm volatile("s_waitcnt vmcnt(0)" ::: "memory")
#define NOVM
#define SBAR __builtin_amdgcn_s_barrier()
#define SCB  __builtin_amdgcn_sched_barrier(0)

#define BUFSZ 32768   // A(16K) + Bhi(8K) + Blo(8K)

// stage units of tile ts_ into buffer bi_ (256 threads)
#define STAGE_A(ts_, bi_)                                                         \
    { unsigned char* la_ = lds + (bi_) * BUFSZ; const int ka_ = (ts_) * 32;       \
      gload_lds16(Ar0 + ka_, la_ + tid * 16);                                     \
      gload_lds16(Ar1 + ka_, la_ + 4096 + tid * 16);                              \
      gload_lds16(Ar2 + ka_, la_ + 8192 + tid * 16);                              \
      gload_lds16(Ar3 + ka_, la_ + 12288 + tid * 16); }
#define STAGE_BH(ts_, bi_)                                                        \
    { unsigned char* la_ = lds + (bi_) * BUFSZ; const int ka_ = (ts_) * 32;       \
      gload_lds16(Br0 + ka_, la_ + 16384 + tid * 16);                             \
      gload_lds16(Br1 + ka_, la_ + 16384 + 4096 + tid * 16); }
#define STAGE_BL(ts_, bi_)                                                        \
    { unsigned char* la_ = lds + (bi_) * BUFSZ; const int ka_ = (ts_) * 32;       \
      gload_lds16(Br0 + 2048 + ka_, la_ + 24576 + tid * 16);                      \
      gload_lds16(Br1 + 2048 + ka_, la_ + 24576 + 4096 + tid * 16); }

// One real-K tile (64 MFMA/wave). R9-proven: NO intra-tile barriers — MFMA
// clusters gated only by compiler-counted lgkmcnt on their own frags; source
// order interleaves reads between clusters.  vmcnt(0)+barrier once per tile.
#define TILE_ONE(t_, BUF_, BUFN_, DO_STAGE_, VM_ASM_)                             \
  {                                                                               \
    const unsigned char* pa_  = lds + (BUF_) * BUFSZ + aoff;                      \
    const unsigned char* pbh_ = lds + (BUF_) * BUFSZ + 16384 + boffU;             \
    const unsigned char* pbl_ = lds + (BUF_) * BUFSZ + 24576 + boffU;             \
    bf16x8 bh_[4], bl_[4], afL_[4], afH_[4];                                      \
    _Pragma("unroll") for (int n_ = 0; n_ < 4; ++n_)                              \
      bh_[n_] = *(const bf16x8*)(pbh_ + n_ * 1024);                               \
    _Pragma("unroll") for (int m_ = 0; m_ < 4; ++m_)                              \
      afL_[m_] = *(const bf16x8*)(pa_ + m_ * 1024);                               \
    if (DO_STAGE_) { STAGE_A((t_) + 1, BUFN_); }                                  \
    __builtin_amdgcn_s_setprio(1);                                                \
    _Pragma("unroll") for (int m_ = 0; m_ < 4; ++m_)                              \
      _Pragma("unroll") for (int n_ = 0; n_ < 4; ++n_)                            \
        acc[m_][n_] = __builtin_amdgcn_mfma_f32_16x16x32_bf16(afL_[m_], bh_[n_],  \
                                                              acc[m_][n_], 0, 0, 0); \
    __builtin_amdgcn_s_setprio(0);                                                \
    _Pragma("unroll") for (int m_ = 0; m_ < 4; ++m_)                              \
      afH_[m_] = *(const bf16x8*)(pa_ + (4 + m_) * 1024);                         \
    if (DO_STAGE_) { STAGE_BH((t_) + 1, BUFN_); }                                 \
    __builtin_amdgcn_s_setprio(1);                                                \
    _Pragma("unroll") for (int m_ = 0; m_ < 4; ++m_)                              \
      _Pragma("unroll") for (int n_ = 0; n_ < 4; ++n_)                            \
        acc[4 + m_][n_] = __builtin_amdgcn_mfma_f32_16x16x32_bf16(afH_[m_], bh_[n_], \
                                                              acc[4 + m_][n_], 0, 0, 0); \
    __builtin_amdgcn_s_setprio(0);                                                \
    _Pragma("unroll") for (int n_ = 0; n_ < 4; ++n_)                              \
      bl_[n_] = *(const bf16x8*)(pbl_ + n_ * 1024);                               \
    if (DO_STAGE_) { STAGE_BL((t_) + 1, BUFN_); }                                 \
    __builtin_amdgcn_s_setprio(1);                                                \
    _Pragma("unroll") for (int m_ = 0; m_ < 4; ++m_)                              \
      _Pragma("unroll") for (int n_ = 0; n_ < 4; ++n_)                            \
        acc[m_][n_] = __builtin_amdgcn_mfma_f32_16x16x32_bf16(afL_[m_], bl_[n_],  \
                                                              acc[m_][n_], 0, 0, 0); \
    _Pragma("unroll") for (int m_ = 0; m_ < 4; ++m_)                              \
      _Pragma("unroll") for (int n_ = 0; n_ < 4; ++n_)                            \
        acc[4 + m_][n_] = __builtin_amdgcn_mfma_f32_16x16x32_bf16(afH_[m_], bl_[n_], \
                                                              acc[4 + m_][n_], 0, 0, 0); \
    __builtin_amdgcn_s_setprio(0);                                                \
    VM_ASM_;                                                                      \
    SBAR; SCB;                                                                    \
  }

#define LTS 136   // epilogue LDS row stride in floats

__global__ __launch_bounds__(256, 2) void gemm_gates(
    const unsigned short* __restrict__ A,   // [4096][2048] bf16 bits
    const unsigned short* __restrict__ B,   // [4096][4096] bf16 bits, permuted cols
    const float* __restrict__ bias,         // [4096] permuted
    const float* __restrict__ cx,           // [4096][1024]
    float* __restrict__ hy,                 // [4096][1024]
    float* __restrict__ cy)                 // [4096][1024]
{
  extern __shared__ unsigned char lds[];    // 71680 B (2 x 32KB + epilogue pad)
  const int tid  = threadIdx.x;
  const int lane = tid & 63;
  const int wave = tid >> 6;                // 0..3
  const int wr = wave >> 1;                 // 0..1  (M)
  const int wc = wave & 1;                  // 0..1  (N)

  // 512 blocks: 16 M-tiles x 32 N-tiles; XCD-chunked swizzle (512 % 8 == 0)
  const int bid = blockIdx.x;
  const int wg  = (bid & 7) * 64 + (bid >> 3);
  const int brow = (wg & 15) * 256;
  const int bcol = (wg >> 4) * 128;         // permuted-column space

  // staging source (inverse-swizzled): chunk c -> p=c>>3, lc=(c&7)^(p&7)
#define CHUNK_SRC(c_, sr_, sk_) \
    { int p_ = (c_) >> 3, lc_ = ((c_) & 7) ^ (p_ & 7); \
      sr_ = p_ * 2 + (lc_ >> 2); sk_ = (lc_ & 3) * 8; }
  int sr, sk;
  CHUNK_SRC(tid,        sr, sk);
  const unsigned short* Ar0 = A + (size_t)(brow + sr) * 2048 + sk;
  const unsigned short* Br0 = B + (size_t)(bcol + sr) * 4096 + sk;
  CHUNK_SRC(tid + 256,  sr, sk);
  const unsigned short* Ar1 = A + (size_t)(brow + sr) * 2048 + sk;
  const unsigned short* Br1 = B + (size_t)(bcol + sr) * 4096 + sk;
  CHUNK_SRC(tid + 512,  sr, sk);
  const unsigned short* Ar2 = A + (size_t)(brow + sr) * 2048 + sk;
  CHUNK_SRC(tid + 768,  sr, sk);
  const unsigned short* Ar3 = A + (size_t)(brow + sr) * 2048 + sk;
#undef CHUNK_SRC

  const int lrh = (lane & 15) >> 1;
  const int chk = ((((lane & 1) << 2) | (lane >> 4)) ^ lrh);
  const int aoff  = wr * 8192 + lrh * 128 + chk * 16;
  const int boffU = wc * 4096 + lrh * 128 + chk * 16;

  f32x4 acc[8][4] = {};

  // prologue: stage tile 0 -> buf0
  STAGE_A(0, 0); STAGE_BH(0, 0); STAGE_BL(0, 0);
  VM0;
  SBAR; SCB;

#pragma unroll 1
  for (int t = 0; t < 63; ++t) {
    TILE_ONE(t, (t & 1), ((t + 1) & 1), 1, VM0);
  }
  TILE_ONE(63, 1, 0, 0, NOVM);

  // ---- fused LSTM epilogue (hardware-exp activations) ----
  // acc[q][n] row = brow + wr*128 + q*16 + (lane>>4)*4 + r
  //           col = bcol + wc*64 + n*16 + (lane&15)   (permuted: col = 4h+g)
  float* LT = (float*)lds;
  const int col_local0 = wc * 64 + (lane & 15);
  const int lrow = (lane >> 4) << 2;
  const int h = tid & 31;                  // 32 h-values per block
  const int hg = (bcol >> 2) + h;

#pragma unroll
  for (int hh = 0; hh < 2; ++hh) {
    __syncthreads();                       // previous half's reads done
#pragma unroll
    for (int m = 0; m < 4; ++m) {
#pragma unroll
      for (int n = 0; n < 4; ++n) {
        const int cl = col_local0 + n * 16;
        const float bv = bias[bcol + cl];
        const int lr0 = wr * 64 + m * 16 + lrow;
#pragma unroll
        for (int r = 0; r < 4; ++r)
          LT[(lr0 + r) * LTS + cl] = acc[hh * 4 + m][n][r] + bv;
      }
    }
    __syncthreads();
#pragma unroll
    for (int i = 0; i < 16; ++i) {
      const int lr = (tid >> 5) * 16 + i;                       // 0..127
      const int grow = brow + ((lr >> 6) << 7) + hh * 64 + (lr & 63);
      const float4 q = *(const float4*)(LT + lr * LTS + 4 * h); // (in,fg,cell,out)
      const size_t oidx = (size_t)grow * 1024 + hg;
      float ing = quantU8(sigmoid_fast(q.x));
      float fg  = quantU8(sigmoid_fast(q.y));
      float cg  = quantS8(tanh_fast(q.z));
      float og  = quantU8(sigmoid_fast(q.w));
      float c0  = cx[oidx];
      float cyv = quantS8((quantS8(fg * c0) + quantS8(ing * cg)) * 0.5f);
      float hyv = quantS8(og * quantS8(tanh_fast(cyv * 2.0f)));
      hy[oidx] = hyv;
      cy[oidx] = cyv;
    }
  }
}

// ---------------- host ----------------
extern "C" void kernel_launch(void* const* d_in, const int* in_sizes, int n_in,
                              void* d_out, int out_size, void* d_ws, size_t ws_size,
                              hipStream_t stream)
{
  const float* input = (const float*)d_in[0];
  const float* hx    = (const float*)d_in[1];
  const float* cx    = (const float*)d_in[2];
  const float* wih   = (const float*)d_in[3];
  const float* whh   = (const float*)d_in[4];
  const float* bih   = (const float*)d_in[5];
  const float* bhh   = (const float*)d_in[6];
  (void)in_sizes; (void)n_in; (void)ws_size;

  uint8_t* ws = (uint8_t*)d_ws;
  unsigned short* A   = (unsigned short*)(ws + WS_A_OFF);
  unsigned short* B   = (unsigned short*)(ws + WS_B_OFF);
  float* biasE        = (float*)(ws + WS_BIAS_OFF);
  uint32_t* mx        = (uint32_t*)(ws + WS_MAX_OFF);

  uint32_t nk[4][2];
#if PART
  for (int i = 0; i < 4; ++i) tf2x32(0u, 42u, 0u, (uint32_t)i, nk[i][0], nk[i][1]);
#else
  {
    uint32_t w0[4], w1[4];
    for (int i = 0; i < 4; ++i) tf2x32(0u, 42u, (uint32_t)i, (uint32_t)(i + 4), w0[i], w1[i]);
    uint32_t out8[8] = {w0[0], w0[1], w0[2], w0[3], w1[0], w1[1], w1[2], w1[3]};
    for (int i = 0; i < 4; ++i) { nk[i][0] = out8[2 * i]; nk[i][1] = out8[2 * i + 1]; }
  }
#endif

  init_max<<<1, 64, 0, stream>>>(mx);
  kmax_all<<<2056, 256, 0, stream>>>((const float4*)wih, (const float4*)whh,
                                     (const float4*)bih, (const float4*)bhh, mx);
  build_all<<<24592, 256, 0, stream>>>(wih, whh, (const float4*)input, (const float4*)hx,
                                       bih, bhh, A, B, biasE, mx,
                                       nk[0][0], nk[0][1], nk[1][0], nk[1][1],
                                       nk[2][0], nk[2][1], nk[3][0], nk[3][1]);

  float* hy = (float*)d_out;
  float* cyp = hy + (size_t)BATCH * 1024;

  (void)hipFuncSetAttribute((const void*)gemm_gates,
                            hipFuncAttributeMaxDynamicSharedMemorySize, 71680);
  gemm_gates<<<dim3(512), dim3(256), 71680, stream>>>(A, B, biasE, cx, hy, cyp);
}